// Round 7
// baseline (584.893 us; speedup 1.0000x reference)
//
#include <hip/hip_runtime.h>
#include <math.h>

#define BB 4
#define CC 256
#define HH 64
#define WW 64
#define NN 4096   // H*W

typedef _Float16 f16x8 __attribute__((ext_vector_type(8)));
typedef float f32x4 __attribute__((ext_vector_type(4)));

// ---------------------------------------------------------------------------
// pad + transpose: xpad[b][pr][pc][ci] = x[b][ci][pr-6][pc-6]  (f16, 0-padded)
// ---------------------------------------------------------------------------
__global__ __launch_bounds__(256) void pad_kernel(
    const float* __restrict__ x, _Float16* __restrict__ xpad)
{
  int blk = blockIdx.x;
  int pr = blk % 76;
  int b  = blk / 76;
  int ci = threadIdx.x;
  int r = pr - 6;
  _Float16* dst = xpad + (((size_t)b*76 + pr)*76)*256 + ci;
  if (r < 0 || r >= HH) {
    for (int pc = 0; pc < 76; ++pc) dst[(size_t)pc*256] = (_Float16)0.f;
  } else {
    const float* src = x + ((size_t)b*CC + ci)*NN + (size_t)r*WW;
    for (int pc = 0; pc < 76; ++pc) {
      int c = pc - 6;
      float v = (c >= 0 && c < WW) ? src[c] : 0.f;
      dst[(size_t)pc*256] = (_Float16)v;
    }
  }
}

// ---------------------------------------------------------------------------
// conv weight convert: dst[t][co][ci] = (f16) src[co][ci][t]
// ---------------------------------------------------------------------------
__global__ __launch_bounds__(256) void wcvt_kernel(
    const float* __restrict__ src, _Float16* __restrict__ dst, int T)
{
  int co = blockIdx.x;
  int ci = threadIdx.x;
  const float* s = src + ((size_t)co*256 + ci)*T;
  for (int t = 0; t < T; ++t)
    dst[(size_t)t*65536 + co*256 + ci] = (_Float16)s[t];
}

// ---------------------------------------------------------------------------
// generic flat f32 -> f16 convert
// ---------------------------------------------------------------------------
__global__ __launch_bounds__(256) void fcvt_kernel(
    const float* __restrict__ src, _Float16* __restrict__ dst, int n)
{
  int i = blockIdx.x * 256 + threadIdx.x;
  if (i < n) dst[i] = (_Float16)src[i];
}

// ---------------------------------------------------------------------------
// implicit-GEMM conv body via MFMA 16x16x32 f16.  T14 reg-prefetch staging:
// issue kh+1's global loads into regs before compute(kh).  Epilogue:
// LDS-transpose (reuse xs, stride 136 f16 aligned) -> ctx_t[b][n][512]+c_off.
// ---------------------------------------------------------------------------
template<int KS, int DIL>
__device__ __forceinline__ void conv_body(
    int blk, const _Float16* __restrict__ xpad, const _Float16* __restrict__ wb,
    const float* __restrict__ bias, _Float16* __restrict__ ctx_t, int c_off,
    char* xs)
{
  int ytile = blk & 31;
  int cot = (blk >> 5) & 1;
  int b = blk >> 6;
  int y0 = ytile * 2;
  int tid = threadIdx.x;
  int lane = tid & 63;
  int wv = tid >> 6;
  int wco = wv >> 1;           // 0..3  -> co strip of 32
  int wsp = wv & 1;            // row y0+wsp
  int l15 = lane & 15;
  int lg  = lane >> 4;

  f32x4 acc[2][4];
  #pragma unroll
  for (int m = 0; m < 2; ++m)
    #pragma unroll
    for (int n = 0; n < 4; ++n) acc[m][n] = (f32x4){0.f, 0.f, 0.f, 0.f};

  uint4 pre[10];
  // issue global loads for plane kh into pre[]
  auto issue = [&](int kh) {
    int prow = 6 + y0 + (kh - KS/2) * DIL;
    const uint4* src = (const uint4*)(xpad + (((size_t)b*76 + prow)*76)*256);
    #pragma unroll
    for (int i = 0; i < 10; ++i) {
      int ch = tid + i*512;               // 16B chunks; 2 rows = 4864 chunks
      if (ch < 4864) pre[i] = src[ch];
    }
  };

  issue(0);
  for (int kh = 0; kh < KS; ++kh) {
    __syncthreads();   // previous compute done reading xs
    #pragma unroll
    for (int i = 0; i < 10; ++i) {
      int ch = tid + i*512;
      if (ch < 4864) {
        int r = ch >> 5, cq = ch & 31;
        *(uint4*)(xs + r*512 + ((cq << 4) ^ ((r & 7) << 4))) = pre[i];
      }
    }
    __syncthreads();
    if (kh + 1 < KS) issue(kh + 1);     // latency hides under compute below
    for (int kw = 0; kw < KS; ++kw) {
      int dx = (kw - KS/2) * DIL;
      int tap = kh*KS + kw;
      const _Float16* wt = wb + ((size_t)tap << 16)
                              + ((size_t)(cot*128 + wco*32 + l15) << 8) + (lg << 3);
      #pragma unroll
      for (int ks = 0; ks < 8; ++ks) {
        f16x8 a0 = *(const f16x8*)(wt + ks*32);
        f16x8 a1 = *(const f16x8*)(wt + 16*256 + ks*32);
        #pragma unroll
        for (int nf = 0; nf < 4; ++nf) {
          int r = wsp*76 + 6 + nf*16 + l15 + dx;
          f16x8 bf = *(const f16x8*)(xs + r*512 + ((ks*64 + (lg << 4)) ^ ((r & 7) << 4)));
          acc[0][nf] = __builtin_amdgcn_mfma_f32_16x16x32_f16(a0, bf, acc[0][nf], 0, 0, 0);
          acc[1][nf] = __builtin_amdgcn_mfma_f32_16x16x32_f16(a1, bf, acc[1][nf], 0, 0, 0);
        }
      }
    }
  }

  // epilogue: LDS transpose tile [128 n][stride 136 co], then coalesced write
  __syncthreads();
  _Float16* ep = (_Float16*)xs;
  #pragma unroll
  for (int m = 0; m < 2; ++m)
    #pragma unroll
    for (int i = 0; i < 4; ++i) {
      int co_l = wco*32 + m*16 + lg*4 + i;
      float bs = bias[cot*128 + co_l];
      #pragma unroll
      for (int nf = 0; nf < 4; ++nf) {
        int n_l = wsp*64 + nf*16 + l15;
        ep[n_l*136 + co_l] = (_Float16)(acc[m][nf][i] + bs);
      }
    }
  __syncthreads();
  const int cbase = c_off + cot*128;
  #pragma unroll
  for (int it = 0; it < 4; ++it) {
    int idx = tid + it*512;
    int n_l = idx >> 4, q = idx & 15;
    f16x8 val = *(const f16x8*)(ep + n_l*136 + q*8);
    *(f16x8*)(ctx_t + ((size_t)b*4096 + (size_t)y0*64 + n_l)*512 + cbase + q*8) = val;
  }
}

// ---------------------------------------------------------------------------
// merged conv dispatch: blocks 0..255 -> conv7 (dil 1), 256..511 -> conv5
// (dil 3).  2 blocks/CU co-resident: one block computes while the other
// stages (independent barrier groups).
// ---------------------------------------------------------------------------
__global__ __launch_bounds__(512) void conv_both_kernel(
    const _Float16* __restrict__ xpad,
    const _Float16* __restrict__ wb7, const _Float16* __restrict__ wb5,
    const float* __restrict__ b7, const float* __restrict__ b5,
    _Float16* __restrict__ ctx_t)
{
  __shared__ __align__(16) char xs[2*76*512];
  if (blockIdx.x < 256)
    conv_body<7, 1>(blockIdx.x, xpad, wb7, b7, ctx_t, 0, xs);
  else
    conv_body<5, 3>(blockIdx.x - 256, xpad, wb5, b5, ctx_t, 256, xs);
}

// ---------------------------------------------------------------------------
// GEMM producing n-major output: out[n][O] = A[n][K] . Wt[o][K]^T + bias
// grid (n-tiles of 64 over 16384, O/64), 64 threads (1 wave), acc 4x4 frags.
// ---------------------------------------------------------------------------
template<int K, int O, int BIASMODE>
__global__ __launch_bounds__(64) void gemm_nmajor_kernel(
    const _Float16* __restrict__ A, const _Float16* __restrict__ Wt,
    const float* __restrict__ bias0, const float* __restrict__ bias1,
    _Float16* __restrict__ outh)
{
  int nt = blockIdx.x;
  int ot = blockIdx.y;
  int lane = threadIdx.x;
  int l15 = lane & 15, lg = lane >> 4;
  int n0 = nt*64, o0 = ot*64;
  f32x4 acc[4][4] = {};
  for (int k0 = 0; k0 < K; k0 += 32) {
    f16x8 a[4], bfr[4];
    #pragma unroll
    for (int f = 0; f < 4; ++f)
      a[f] = *(const f16x8*)(A + (size_t)(n0 + f*16 + l15)*K + k0 + lg*8);
    #pragma unroll
    for (int f = 0; f < 4; ++f)
      bfr[f] = *(const f16x8*)(Wt + (size_t)(o0 + f*16 + l15)*K + k0 + lg*8);
    #pragma unroll
    for (int i = 0; i < 4; ++i)
      #pragma unroll
      for (int j = 0; j < 4; ++j)
        acc[i][j] = __builtin_amdgcn_mfma_f32_16x16x32_f16(a[i], bfr[j], acc[i][j], 0, 0, 0);
  }
  #pragma unroll
  for (int i = 0; i < 4; ++i)
    #pragma unroll
    for (int j = 0; j < 4; ++j)
      #pragma unroll
      for (int r = 0; r < 4; ++r) {
        int n = n0 + i*16 + lg*4 + r;
        int o = o0 + j*16 + l15;
        float bs = (BIASMODE == 0) ? bias0[o] : (o < 32 ? bias0[o] : bias1[o - 32]);
        outh[(size_t)n*O + o] = (_Float16)(acc[i][j][r] + bs);
      }
}

// ---------------------------------------------------------------------------
// v GEMM: v[b][c][n] = Wv[c][m] . multi_t[n][m]^T + bias  (c-major out)
// ---------------------------------------------------------------------------
__global__ __launch_bounds__(64) void gemm_v_kernel(
    const _Float16* __restrict__ M, const _Float16* __restrict__ Wv,
    const float* __restrict__ bias, _Float16* __restrict__ v)
{
  int nt = blockIdx.x;          // over 16384/64
  int ct = blockIdx.y;          // 0..3
  int lane = threadIdx.x;
  int l15 = lane & 15, lg = lane >> 4;
  int n0 = nt*64, c0 = ct*64;
  f32x4 acc[4][4] = {};
  for (int k0 = 0; k0 < 256; k0 += 32) {
    f16x8 a[4], bfr[4];
    #pragma unroll
    for (int f = 0; f < 4; ++f)
      a[f] = *(const f16x8*)(Wv + (size_t)(c0 + f*16 + l15)*256 + k0 + lg*8);
    #pragma unroll
    for (int f = 0; f < 4; ++f)
      bfr[f] = *(const f16x8*)(M + (size_t)(n0 + f*16 + l15)*256 + k0 + lg*8);
    #pragma unroll
    for (int i = 0; i < 4; ++i)
      #pragma unroll
      for (int j = 0; j < 4; ++j)
        acc[i][j] = __builtin_amdgcn_mfma_f32_16x16x32_f16(a[i], bfr[j], acc[i][j], 0, 0, 0);
  }
  #pragma unroll
  for (int i = 0; i < 4; ++i)
    #pragma unroll
    for (int j = 0; j < 4; ++j)
      #pragma unroll
      for (int r = 0; r < 4; ++r) {
        int c = c0 + i*16 + lg*4 + r;
        int n_abs = n0 + j*16 + l15;
        int b = n_abs >> 12, n = n_abs & 4095;
        v[((size_t)(b*256 + c))*4096 + n] = (_Float16)(acc[i][j][r] + bias[c]);
      }
}

// ---------------------------------------------------------------------------
// attention pass A: per-row running max + sum(exp) over an n-half.
// qkt layout [16384][64] f16: cols 0..31 = q, 32..63 = k.
// grid 512 = b(4) x mt(64) x nh(2), 256 threads (4 waves, 16 m-rows each).
// ---------------------------------------------------------------------------
__global__ __launch_bounds__(256) void attn_stats_kernel(
    const _Float16* __restrict__ qh,
    float* __restrict__ rowmaxP, float* __restrict__ rowsumP)
{
  int blk = blockIdx.x;
  int b = blk >> 7, mt = (blk >> 1) & 63, nh = blk & 1;
  int tid = threadIdx.x, lane = tid & 63, w = tid >> 6;
  int l15 = lane & 15, lg = lane >> 4;
  size_t bN = (size_t)b * 4096;
  int mrow = mt*64 + w*16;
  f16x8 ah = *(const f16x8*)(qh + (bN + mrow + l15)*64 + lg*8);
  float rm[4] = {-3e38f, -3e38f, -3e38f, -3e38f};
  float sm[4] = {0.f, 0.f, 0.f, 0.f};
  for (int n0 = nh*2048; n0 < nh*2048 + 2048; n0 += 16) {
    f16x8 bh = *(const f16x8*)(qh + (bN + n0 + l15)*64 + 32 + lg*8);
    f32x4 s = {};
    s = __builtin_amdgcn_mfma_f32_16x16x32_f16(ah, bh, s, 0, 0, 0);
    #pragma unroll
    for (int i = 0; i < 4; ++i) {
      float nm = fmaxf(rm[i], s[i]);
      sm[i] = sm[i]*__expf(rm[i] - nm) + __expf(s[i] - nm);
      rm[i] = nm;
    }
  }
  #pragma unroll
  for (int off = 1; off <= 8; off <<= 1) {
    #pragma unroll
    for (int i = 0; i < 4; ++i) {
      float rmo = __shfl_xor(rm[i], off);
      float smo = __shfl_xor(sm[i], off);
      float M = fmaxf(rm[i], rmo);
      sm[i] = sm[i]*__expf(rm[i] - M) + smo*__expf(rmo - M);
      rm[i] = M;
    }
  }
  if (l15 == 0) {
    #pragma unroll
    for (int i = 0; i < 4; ++i) {
      size_t idx = (size_t)nh*16384 + bN + mrow + lg*4 + i;
      rowmaxP[idx] = rm[i];
      rowsumP[idx] = sm[i];
    }
  }
}

// ---------------------------------------------------------------------------
// attention pass B: O[m64][c256] = P . V^T with P recomputed per 32-n chunk.
// grid 256 = b(4) x mt(64), 512 threads (8 waves).
// vs/pl strides = 40 f16 (80B): 16B-aligned rows for ds_read_b128.
// ---------------------------------------------------------------------------
__global__ __launch_bounds__(512) void attn_out_kernel(
    const _Float16* __restrict__ qh, const _Float16* __restrict__ v,
    const float* __restrict__ rowmaxP, const float* __restrict__ rowsumP,
    const float* __restrict__ mask, float* __restrict__ out)
{
  __shared__ union U {
    struct { __align__(16) _Float16 vs[256*40]; __align__(16) _Float16 pl[64*40]; } s;
    float epi[256*68];
  } u;
  int blk = blockIdx.x;
  int b = blk >> 6, mt = blk & 63;
  int tid = threadIdx.x, lane = tid & 63, w = tid >> 6;
  int l15 = lane & 15, lg = lane >> 4;
  size_t bN = (size_t)b * 4096;
  int m0 = mt*64;

  // QK role
  int mf = w >> 1, nf2 = w & 1;
  f16x8 ah = *(const f16x8*)(qh + (bN + m0 + mf*16 + l15)*64 + lg*8);
  float rm[4], rsi[4];
  #pragma unroll
  for (int i = 0; i < 4; ++i) {
    size_t m = bN + m0 + mf*16 + lg*4 + i;
    float r0 = rowmaxP[m], r1 = rowmaxP[16384 + m];
    float s0 = rowsumP[m], s1 = rowsumP[16384 + m];
    float M = fmaxf(r0, r1);
    rm[i] = M;
    rsi[i] = 1.0f / (s0*__expf(r0 - M) + s1*__expf(r1 - M));
  }
  // PV role
  int mh = w >> 2, cw = (w & 3)*64;
  f32x4 acc[2][4] = {};
  const _Float16* vb = v + (size_t)b*256*4096;

  for (int n0 = 0; n0 < 4096; n0 += 32) {
    // stage v tile [256 c][32 n] (stride 40 f16)
    #pragma unroll
    for (int it = 0; it < 2; ++it) {
      int idx = tid + it*512;
      int c = idx >> 2, q = idx & 3;
      *(f16x8*)(u.s.vs + c*40 + q*8) = *(const f16x8*)(vb + (size_t)c*4096 + n0 + q*8);
    }
    // QK + exp -> P (f16) in LDS
    {
      f16x8 bh = *(const f16x8*)(qh + (bN + n0 + nf2*16 + l15)*64 + 32 + lg*8);
      f32x4 s = {};
      s = __builtin_amdgcn_mfma_f32_16x16x32_f16(ah, bh, s, 0, 0, 0);
      #pragma unroll
      for (int i = 0; i < 4; ++i) {
        float p = __expf(s[i] - rm[i]) * rsi[i];
        u.s.pl[(mf*16 + lg*4 + i)*40 + nf2*16 + l15] = (_Float16)p;
      }
    }
    __syncthreads();
    // PV
    {
      f16x8 pa[2], pb[4];
      #pragma unroll
      for (int af = 0; af < 2; ++af)
        pa[af] = *(const f16x8*)(u.s.pl + (mh*32 + af*16 + l15)*40 + lg*8);
      #pragma unroll
      for (int bf = 0; bf < 4; ++bf)
        pb[bf] = *(const f16x8*)(u.s.vs + (cw + bf*16 + l15)*40 + lg*8);
      #pragma unroll
      for (int af = 0; af < 2; ++af)
        #pragma unroll
        for (int bf = 0; bf < 4; ++bf)
          acc[af][bf] = __builtin_amdgcn_mfma_f32_16x16x32_f16(pa[af], pb[bf], acc[af][bf], 0, 0, 0);
    }
    __syncthreads();
  }

  // epilogue: transpose via LDS, apply (1+mask), write out[b][c][m]
  #pragma unroll
  for (int af = 0; af < 2; ++af)
    #pragma unroll
    for (int bf = 0; bf < 4; ++bf)
      #pragma unroll
      for (int r = 0; r < 4; ++r) {
        int c = cw + bf*16 + l15;
        int ml = mh*32 + af*16 + lg*4 + r;
        u.epi[c*68 + ml] = acc[af][bf][r];
      }
  __syncthreads();
  const float* mb = mask + (size_t)b*65536 + (size_t)(mt*4)*256;
  #pragma unroll
  for (int it = 0; it < 8; ++it) {
    int idx = tid + it*512;
    int c = idx >> 4, q = idx & 15;
    f32x4 val = *(const f32x4*)(u.epi + c*68 + q*4);
    f32x4 o4;
    #pragma unroll
    for (int jj = 0; jj < 4; ++jj) {
      int xcol = q*4 + jj;
      o4[jj] = val[jj] * (1.0f + mb[xcol*4]);
    }
    *(f32x4*)(out + ((size_t)b*256 + c)*4096 + m0 + q*4) = o4;
  }
}

// ---------------------------------------------------------------------------
extern "C" void kernel_launch(void* const* d_in, const int* in_sizes, int n_in,
                              void* d_out, int out_size, void* d_ws, size_t ws_size,
                              hipStream_t stream)
{
  (void)in_sizes; (void)n_in; (void)out_size; (void)ws_size;
  const float* x      = (const float*)d_in[0];
  const float* mask   = (const float*)d_in[1];
  const float* w_ctx  = (const float*)d_in[2];
  const float* b_ctx  = (const float*)d_in[3];
  const float* w_wide = (const float*)d_in[4];
  const float* b_wide = (const float*)d_in[5];
  const float* w_comb = (const float*)d_in[6];
  const float* b_comb = (const float*)d_in[7];
  const float* w_q    = (const float*)d_in[8];
  const float* b_q    = (const float*)d_in[9];
  const float* w_k    = (const float*)d_in[10];
  const float* b_k    = (const float*)d_in[11];
  const float* w_v    = (const float*)d_in[12];
  const float* b_v    = (const float*)d_in[13];
  float* out = (float*)d_out;

  float* ws = (float*)d_ws;
  // --- phase-aliased layout (float offsets). Total 9,682,944 fl = 38.7 MB.
  // Phase 1 (pre/conv):
  _Float16* xpad    = (_Float16*)(ws);             // [0, 2,957,312)
  _Float16* wb7     = (_Float16*)(ws + 2957312);   // 49*65536 f16
  _Float16* wb5     = (_Float16*)(ws + 4562944);   // 25*65536 f16
  _Float16* ctx_t   = (_Float16*)(ws + 5382144);   // 16384*512 f16
  _Float16* wcombH  = (_Float16*)(ws + 9576448);   // 256*512 f16
  _Float16* wqkH    = (_Float16*)(ws + 9641984);   // 64*256 f16
  _Float16* wvH     = (_Float16*)(ws + 9650176);   // 256*256 f16
  // Phase 2 (after convs; xpad/wb7/wb5 dead, ctx_t live):
  _Float16* multi_t = (_Float16*)(ws);             // 16384*256 f16
  _Float16* qkt_h   = (_Float16*)(ws + 2097152);   // 16384*64 f16
  float*    rowmaxP = ws + 2621440;                // 2*16384 f32
  float*    rowsumP = ws + 2654208;                // 2*16384 f32
  // Phase 3 (after combine; ctx_t dead):
  _Float16* vbuf    = (_Float16*)(ws + 5382144);   // 4*256*4096 f16

  pad_kernel<<<BB*76, 256, 0, stream>>>(x, xpad);
  wcvt_kernel<<<256, 256, 0, stream>>>(w_ctx, wb7, 49);
  wcvt_kernel<<<256, 256, 0, stream>>>(w_wide, wb5, 25);
  fcvt_kernel<<<512, 256, 0, stream>>>(w_comb, wcombH, 131072);
  fcvt_kernel<<<32, 256, 0, stream>>>(w_q, wqkH, 8192);
  fcvt_kernel<<<32, 256, 0, stream>>>(w_k, wqkH + 8192, 8192);
  fcvt_kernel<<<256, 256, 0, stream>>>(w_v, wvH, 65536);

  conv_both_kernel<<<512, 512, 0, stream>>>(xpad, wb7, wb5, b_ctx, b_wide, ctx_t);

  gemm_nmajor_kernel<512, 256, 0><<<dim3(256, 4), 64, 0, stream>>>(
      ctx_t, wcombH, b_comb, nullptr, multi_t);
  gemm_nmajor_kernel<256, 64, 1><<<dim3(256, 1), 64, 0, stream>>>(
      multi_t, wqkH, b_q, b_k, qkt_h);
  gemm_v_kernel<<<dim3(256, 4), 64, 0, stream>>>(multi_t, wvH, b_v, vbuf);

  attn_stats_kernel<<<512, 256, 0, stream>>>(qkt_h, rowmaxP, rowsumP);
  attn_out_kernel<<<256, 512, 0, stream>>>(qkt_h, vbuf, rowmaxP, rowsumP,
                                           mask, out);
}

// Round 8
// 529.083 us; speedup vs baseline: 1.1055x; 1.1055x over previous
//
#include <hip/hip_runtime.h>
#include <math.h>

#define BB 4
#define CC 256
#define HH 64
#define WW 64
#define NN 4096   // H*W

typedef _Float16 f16x8 __attribute__((ext_vector_type(8)));
typedef float f32x4 __attribute__((ext_vector_type(4)));

// ---------------------------------------------------------------------------
// pad + transpose: xpad[b][pr][pc][ci] = x[b][ci][pr-6][pc-6]  (f16, 0-padded)
// ---------------------------------------------------------------------------
__global__ __launch_bounds__(256) void pad_kernel(
    const float* __restrict__ x, _Float16* __restrict__ xpad)
{
  int blk = blockIdx.x;
  int pr = blk % 76;
  int b  = blk / 76;
  int ci = threadIdx.x;
  int r = pr - 6;
  _Float16* dst = xpad + (((size_t)b*76 + pr)*76)*256 + ci;
  if (r < 0 || r >= HH) {
    for (int pc = 0; pc < 76; ++pc) dst[(size_t)pc*256] = (_Float16)0.f;
  } else {
    const float* src = x + ((size_t)b*CC + ci)*NN + (size_t)r*WW;
    for (int pc = 0; pc < 76; ++pc) {
      int c = pc - 6;
      float v = (c >= 0 && c < WW) ? src[c] : 0.f;
      dst[(size_t)pc*256] = (_Float16)v;
    }
  }
}

// ---------------------------------------------------------------------------
// conv weight convert: dst[t][co][ci] = (f16) src[co][ci][t]
// ---------------------------------------------------------------------------
__global__ __launch_bounds__(256) void wcvt_kernel(
    const float* __restrict__ src, _Float16* __restrict__ dst, int T)
{
  int co = blockIdx.x;
  int ci = threadIdx.x;
  const float* s = src + ((size_t)co*256 + ci)*T;
  for (int t = 0; t < T; ++t)
    dst[(size_t)t*65536 + co*256 + ci] = (_Float16)s[t];
}

// ---------------------------------------------------------------------------
// generic flat f32 -> f16 convert
// ---------------------------------------------------------------------------
__global__ __launch_bounds__(256) void fcvt_kernel(
    const float* __restrict__ src, _Float16* __restrict__ dst, int n)
{
  int i = blockIdx.x * 256 + threadIdx.x;
  if (i < n) dst[i] = (_Float16)src[i];
}

// ---------------------------------------------------------------------------
// implicit-GEMM conv body via MFMA 16x16x32 f16.  Round-6 staging (direct
// global->LDS store, one live uint4 per iter -- no spill).  Epilogue:
// LDS-transpose (reuse xs, stride 136 f16 aligned) -> ctx_t[b][n][512]+c_off.
// ---------------------------------------------------------------------------
template<int KS, int DIL>
__device__ __forceinline__ void conv_body(
    int blk, const _Float16* __restrict__ xpad, const _Float16* __restrict__ wb,
    const float* __restrict__ bias, _Float16* __restrict__ ctx_t, int c_off,
    char* xs)
{
  int ytile = blk & 31;
  int cot = (blk >> 5) & 1;
  int b = blk >> 6;
  int y0 = ytile * 2;
  int tid = threadIdx.x;
  int lane = tid & 63;
  int wv = tid >> 6;
  int wco = wv >> 1;           // 0..3  -> co strip of 32
  int wsp = wv & 1;            // row y0+wsp
  int l15 = lane & 15;
  int lg  = lane >> 4;

  f32x4 acc[2][4];
  #pragma unroll
  for (int m = 0; m < 2; ++m)
    #pragma unroll
    for (int n = 0; n < 4; ++n) acc[m][n] = (f32x4){0.f, 0.f, 0.f, 0.f};

  for (int kh = 0; kh < KS; ++kh) {
    int prow = 6 + y0 + (kh - KS/2) * DIL;
    const uint4* src = (const uint4*)(xpad + (((size_t)b*76 + prow)*76)*256);
    __syncthreads();   // previous compute done reading xs
    #pragma unroll
    for (int i = 0; i < 10; ++i) {
      int ch = tid + i*512;               // 16B chunks; 2 rows = 4864 chunks
      if (ch < 4864) {
        uint4 v = src[ch];
        int r = ch >> 5, cq = ch & 31;
        *(uint4*)(xs + r*512 + ((cq << 4) ^ ((r & 7) << 4))) = v;
      }
    }
    __syncthreads();
    for (int kw = 0; kw < KS; ++kw) {
      int dx = (kw - KS/2) * DIL;
      int tap = kh*KS + kw;
      const _Float16* wt = wb + ((size_t)tap << 16)
                              + ((size_t)(cot*128 + wco*32 + l15) << 8) + (lg << 3);
      #pragma unroll
      for (int ks = 0; ks < 8; ++ks) {
        f16x8 a0 = *(const f16x8*)(wt + ks*32);
        f16x8 a1 = *(const f16x8*)(wt + 16*256 + ks*32);
        #pragma unroll
        for (int nf = 0; nf < 4; ++nf) {
          int r = wsp*76 + 6 + nf*16 + l15 + dx;
          f16x8 bf = *(const f16x8*)(xs + r*512 + ((ks*64 + (lg << 4)) ^ ((r & 7) << 4)));
          acc[0][nf] = __builtin_amdgcn_mfma_f32_16x16x32_f16(a0, bf, acc[0][nf], 0, 0, 0);
          acc[1][nf] = __builtin_amdgcn_mfma_f32_16x16x32_f16(a1, bf, acc[1][nf], 0, 0, 0);
        }
      }
    }
  }

  // epilogue: LDS transpose tile [128 n][stride 136 co], then coalesced write
  __syncthreads();
  _Float16* ep = (_Float16*)xs;
  #pragma unroll
  for (int m = 0; m < 2; ++m)
    #pragma unroll
    for (int i = 0; i < 4; ++i) {
      int co_l = wco*32 + m*16 + lg*4 + i;
      float bs = bias[cot*128 + co_l];
      #pragma unroll
      for (int nf = 0; nf < 4; ++nf) {
        int n_l = wsp*64 + nf*16 + l15;
        ep[n_l*136 + co_l] = (_Float16)(acc[m][nf][i] + bs);
      }
    }
  __syncthreads();
  const int cbase = c_off + cot*128;
  #pragma unroll
  for (int it = 0; it < 4; ++it) {
    int idx = tid + it*512;
    int n_l = idx >> 4, q = idx & 15;
    f16x8 val = *(const f16x8*)(ep + n_l*136 + q*8);
    *(f16x8*)(ctx_t + ((size_t)b*4096 + (size_t)y0*64 + n_l)*512 + cbase + q*8) = val;
  }
}

// ---------------------------------------------------------------------------
// merged conv dispatch: blocks 0..255 -> conv7 (dil 1), 256..511 -> conv5
// (dil 3).  __launch_bounds__(512,4): 4 waves/SIMD = 2 blocks/CU co-resident
// (LDS 2x77824 = 155,648 <= 163,840), cross-block overlap covers staging.
// ---------------------------------------------------------------------------
__global__ __launch_bounds__(512, 4) void conv_both_kernel(
    const _Float16* __restrict__ xpad,
    const _Float16* __restrict__ wb7, const _Float16* __restrict__ wb5,
    const float* __restrict__ b7, const float* __restrict__ b5,
    _Float16* __restrict__ ctx_t)
{
  __shared__ __align__(16) char xs[2*76*512];
  if (blockIdx.x < 256)
    conv_body<7, 1>(blockIdx.x, xpad, wb7, b7, ctx_t, 0, xs);
  else
    conv_body<5, 3>(blockIdx.x - 256, xpad, wb5, b5, ctx_t, 256, xs);
}

// ---------------------------------------------------------------------------
// GEMM producing n-major output: out[n][O] = A[n][K] . Wt[o][K]^T + bias
// grid (n-tiles of 64 over 16384, O/64), 64 threads (1 wave), acc 4x4 frags.
// ---------------------------------------------------------------------------
template<int K, int O, int BIASMODE>
__global__ __launch_bounds__(64) void gemm_nmajor_kernel(
    const _Float16* __restrict__ A, const _Float16* __restrict__ Wt,
    const float* __restrict__ bias0, const float* __restrict__ bias1,
    _Float16* __restrict__ outh)
{
  int nt = blockIdx.x;
  int ot = blockIdx.y;
  int lane = threadIdx.x;
  int l15 = lane & 15, lg = lane >> 4;
  int n0 = nt*64, o0 = ot*64;
  f32x4 acc[4][4] = {};
  for (int k0 = 0; k0 < K; k0 += 32) {
    f16x8 a[4], bfr[4];
    #pragma unroll
    for (int f = 0; f < 4; ++f)
      a[f] = *(const f16x8*)(A + (size_t)(n0 + f*16 + l15)*K + k0 + lg*8);
    #pragma unroll
    for (int f = 0; f < 4; ++f)
      bfr[f] = *(const f16x8*)(Wt + (size_t)(o0 + f*16 + l15)*K + k0 + lg*8);
    #pragma unroll
    for (int i = 0; i < 4; ++i)
      #pragma unroll
      for (int j = 0; j < 4; ++j)
        acc[i][j] = __builtin_amdgcn_mfma_f32_16x16x32_f16(a[i], bfr[j], acc[i][j], 0, 0, 0);
  }
  #pragma unroll
  for (int i = 0; i < 4; ++i)
    #pragma unroll
    for (int j = 0; j < 4; ++j)
      #pragma unroll
      for (int r = 0; r < 4; ++r) {
        int n = n0 + i*16 + lg*4 + r;
        int o = o0 + j*16 + l15;
        float bs = (BIASMODE == 0) ? bias0[o] : (o < 32 ? bias0[o] : bias1[o - 32]);
        outh[(size_t)n*O + o] = (_Float16)(acc[i][j][r] + bs);
      }
}

// ---------------------------------------------------------------------------
// v GEMM: v[b][c][n] = Wv[c][m] . multi_t[n][m]^T + bias  (c-major out)
// ---------------------------------------------------------------------------
__global__ __launch_bounds__(64) void gemm_v_kernel(
    const _Float16* __restrict__ M, const _Float16* __restrict__ Wv,
    const float* __restrict__ bias, _Float16* __restrict__ v)
{
  int nt = blockIdx.x;          // over 16384/64
  int ct = blockIdx.y;          // 0..3
  int lane = threadIdx.x;
  int l15 = lane & 15, lg = lane >> 4;
  int n0 = nt*64, c0 = ct*64;
  f32x4 acc[4][4] = {};
  for (int k0 = 0; k0 < 256; k0 += 32) {
    f16x8 a[4], bfr[4];
    #pragma unroll
    for (int f = 0; f < 4; ++f)
      a[f] = *(const f16x8*)(Wv + (size_t)(c0 + f*16 + l15)*256 + k0 + lg*8);
    #pragma unroll
    for (int f = 0; f < 4; ++f)
      bfr[f] = *(const f16x8*)(M + (size_t)(n0 + f*16 + l15)*256 + k0 + lg*8);
    #pragma unroll
    for (int i = 0; i < 4; ++i)
      #pragma unroll
      for (int j = 0; j < 4; ++j)
        acc[i][j] = __builtin_amdgcn_mfma_f32_16x16x32_f16(a[i], bfr[j], acc[i][j], 0, 0, 0);
  }
  #pragma unroll
  for (int i = 0; i < 4; ++i)
    #pragma unroll
    for (int j = 0; j < 4; ++j)
      #pragma unroll
      for (int r = 0; r < 4; ++r) {
        int c = c0 + i*16 + lg*4 + r;
        int n_abs = n0 + j*16 + l15;
        int b = n_abs >> 12, n = n_abs & 4095;
        v[((size_t)(b*256 + c))*4096 + n] = (_Float16)(acc[i][j][r] + bias[c]);
      }
}

// ---------------------------------------------------------------------------
// attention pass A: per-row running max + sum(exp) over an n-half.
// qkt layout [16384][64] f16: cols 0..31 = q, 32..63 = k.
// grid 512 = b(4) x mt(64) x nh(2), 256 threads (4 waves, 16 m-rows each).
// ---------------------------------------------------------------------------
__global__ __launch_bounds__(256) void attn_stats_kernel(
    const _Float16* __restrict__ qh,
    float* __restrict__ rowmaxP, float* __restrict__ rowsumP)
{
  int blk = blockIdx.x;
  int b = blk >> 7, mt = (blk >> 1) & 63, nh = blk & 1;
  int tid = threadIdx.x, lane = tid & 63, w = tid >> 6;
  int l15 = lane & 15, lg = lane >> 4;
  size_t bN = (size_t)b * 4096;
  int mrow = mt*64 + w*16;
  f16x8 ah = *(const f16x8*)(qh + (bN + mrow + l15)*64 + lg*8);
  float rm[4] = {-3e38f, -3e38f, -3e38f, -3e38f};
  float sm[4] = {0.f, 0.f, 0.f, 0.f};
  for (int n0 = nh*2048; n0 < nh*2048 + 2048; n0 += 16) {
    f16x8 bh = *(const f16x8*)(qh + (bN + n0 + l15)*64 + 32 + lg*8);
    f32x4 s = {};
    s = __builtin_amdgcn_mfma_f32_16x16x32_f16(ah, bh, s, 0, 0, 0);
    #pragma unroll
    for (int i = 0; i < 4; ++i) {
      float nm = fmaxf(rm[i], s[i]);
      sm[i] = sm[i]*__expf(rm[i] - nm) + __expf(s[i] - nm);
      rm[i] = nm;
    }
  }
  #pragma unroll
  for (int off = 1; off <= 8; off <<= 1) {
    #pragma unroll
    for (int i = 0; i < 4; ++i) {
      float rmo = __shfl_xor(rm[i], off);
      float smo = __shfl_xor(sm[i], off);
      float M = fmaxf(rm[i], rmo);
      sm[i] = sm[i]*__expf(rm[i] - M) + smo*__expf(rmo - M);
      rm[i] = M;
    }
  }
  if (l15 == 0) {
    #pragma unroll
    for (int i = 0; i < 4; ++i) {
      size_t idx = (size_t)nh*16384 + bN + mrow + lg*4 + i;
      rowmaxP[idx] = rm[i];
      rowsumP[idx] = sm[i];
    }
  }
}

// ---------------------------------------------------------------------------
// attention pass B: O[m64][c256] = P . V^T with P recomputed per 32-n chunk.
// grid 256 = b(4) x mt(64), 512 threads (8 waves).
// vs/pl strides = 40 f16 (80B): 16B-aligned rows for ds_read_b128.
// ---------------------------------------------------------------------------
__global__ __launch_bounds__(512) void attn_out_kernel(
    const _Float16* __restrict__ qh, const _Float16* __restrict__ v,
    const float* __restrict__ rowmaxP, const float* __restrict__ rowsumP,
    const float* __restrict__ mask, float* __restrict__ out)
{
  __shared__ union U {
    struct { __align__(16) _Float16 vs[256*40]; __align__(16) _Float16 pl[64*40]; } s;
    float epi[256*68];
  } u;
  int blk = blockIdx.x;
  int b = blk >> 6, mt = blk & 63;
  int tid = threadIdx.x, lane = tid & 63, w = tid >> 6;
  int l15 = lane & 15, lg = lane >> 4;
  size_t bN = (size_t)b * 4096;
  int m0 = mt*64;

  // QK role
  int mf = w >> 1, nf2 = w & 1;
  f16x8 ah = *(const f16x8*)(qh + (bN + m0 + mf*16 + l15)*64 + lg*8);
  float rm[4], rsi[4];
  #pragma unroll
  for (int i = 0; i < 4; ++i) {
    size_t m = bN + m0 + mf*16 + lg*4 + i;
    float r0 = rowmaxP[m], r1 = rowmaxP[16384 + m];
    float s0 = rowsumP[m], s1 = rowsumP[16384 + m];
    float M = fmaxf(r0, r1);
    rm[i] = M;
    rsi[i] = 1.0f / (s0*__expf(r0 - M) + s1*__expf(r1 - M));
  }
  // PV role
  int mh = w >> 2, cw = (w & 3)*64;
  f32x4 acc[2][4] = {};
  const _Float16* vb = v + (size_t)b*256*4096;

  for (int n0 = 0; n0 < 4096; n0 += 32) {
    // stage v tile [256 c][32 n] (stride 40 f16)
    #pragma unroll
    for (int it = 0; it < 2; ++it) {
      int idx = tid + it*512;
      int c = idx >> 2, q = idx & 3;
      *(f16x8*)(u.s.vs + c*40 + q*8) = *(const f16x8*)(vb + (size_t)c*4096 + n0 + q*8);
    }
    // QK + exp -> P (f16) in LDS
    {
      f16x8 bh = *(const f16x8*)(qh + (bN + n0 + nf2*16 + l15)*64 + 32 + lg*8);
      f32x4 s = {};
      s = __builtin_amdgcn_mfma_f32_16x16x32_f16(ah, bh, s, 0, 0, 0);
      #pragma unroll
      for (int i = 0; i < 4; ++i) {
        float p = __expf(s[i] - rm[i]) * rsi[i];
        u.s.pl[(mf*16 + lg*4 + i)*40 + nf2*16 + l15] = (_Float16)p;
      }
    }
    __syncthreads();
    // PV
    {
      f16x8 pa[2], pb[4];
      #pragma unroll
      for (int af = 0; af < 2; ++af)
        pa[af] = *(const f16x8*)(u.s.pl + (mh*32 + af*16 + l15)*40 + lg*8);
      #pragma unroll
      for (int bf = 0; bf < 4; ++bf)
        pb[bf] = *(const f16x8*)(u.s.vs + (cw + bf*16 + l15)*40 + lg*8);
      #pragma unroll
      for (int af = 0; af < 2; ++af)
        #pragma unroll
        for (int bf = 0; bf < 4; ++bf)
          acc[af][bf] = __builtin_amdgcn_mfma_f32_16x16x32_f16(pa[af], pb[bf], acc[af][bf], 0, 0, 0);
    }
    __syncthreads();
  }

  // epilogue: transpose via LDS, apply (1+mask), write out[b][c][m]
  #pragma unroll
  for (int af = 0; af < 2; ++af)
    #pragma unroll
    for (int bf = 0; bf < 4; ++bf)
      #pragma unroll
      for (int r = 0; r < 4; ++r) {
        int c = cw + bf*16 + l15;
        int ml = mh*32 + af*16 + lg*4 + r;
        u.epi[c*68 + ml] = acc[af][bf][r];
      }
  __syncthreads();
  const float* mb = mask + (size_t)b*65536 + (size_t)(mt*4)*256;
  #pragma unroll
  for (int it = 0; it < 8; ++it) {
    int idx = tid + it*512;
    int c = idx >> 4, q = idx & 15;
    f32x4 val = *(const f32x4*)(u.epi + c*68 + q*4);
    f32x4 o4;
    #pragma unroll
    for (int jj = 0; jj < 4; ++jj) {
      int xcol = q*4 + jj;
      o4[jj] = val[jj] * (1.0f + mb[xcol*4]);
    }
    *(f32x4*)(out + ((size_t)b*256 + c)*4096 + m0 + q*4) = o4;
  }
}

// ---------------------------------------------------------------------------
extern "C" void kernel_launch(void* const* d_in, const int* in_sizes, int n_in,
                              void* d_out, int out_size, void* d_ws, size_t ws_size,
                              hipStream_t stream)
{
  (void)in_sizes; (void)n_in; (void)out_size; (void)ws_size;
  const float* x      = (const float*)d_in[0];
  const float* mask   = (const float*)d_in[1];
  const float* w_ctx  = (const float*)d_in[2];
  const float* b_ctx  = (const float*)d_in[3];
  const float* w_wide = (const float*)d_in[4];
  const float* b_wide = (const float*)d_in[5];
  const float* w_comb = (const float*)d_in[6];
  const float* b_comb = (const float*)d_in[7];
  const float* w_q    = (const float*)d_in[8];
  const float* b_q    = (const float*)d_in[9];
  const float* w_k    = (const float*)d_in[10];
  const float* b_k    = (const float*)d_in[11];
  const float* w_v    = (const float*)d_in[12];
  const float* b_v    = (const float*)d_in[13];
  float* out = (float*)d_out;

  float* ws = (float*)d_ws;
  // --- phase-aliased layout (float offsets). Total 9,682,944 fl = 38.7 MB.
  // Phase 1 (pre/conv):
  _Float16* xpad    = (_Float16*)(ws);             // [0, 2,957,312)
  _Float16* wb7     = (_Float16*)(ws + 2957312);   // 49*65536 f16
  _Float16* wb5     = (_Float16*)(ws + 4562944);   // 25*65536 f16
  _Float16* ctx_t   = (_Float16*)(ws + 5382144);   // 16384*512 f16
  _Float16* wcombH  = (_Float16*)(ws + 9576448);   // 256*512 f16
  _Float16* wqkH    = (_Float16*)(ws + 9641984);   // 64*256 f16
  _Float16* wvH     = (_Float16*)(ws + 9650176);   // 256*256 f16
  // Phase 2 (after convs; xpad/wb7/wb5 dead, ctx_t live):
  _Float16* multi_t = (_Float16*)(ws);             // 16384*256 f16
  _Float16* qkt_h   = (_Float16*)(ws + 2097152);   // 16384*64 f16
  float*    rowmaxP = ws + 2621440;                // 2*16384 f32
  float*    rowsumP = ws + 2654208;                // 2*16384 f32
  // Phase 3 (after combine; ctx_t dead):
  _Float16* vbuf    = (_Float16*)(ws + 5382144);   // 4*256*4096 f16

  pad_kernel<<<BB*76, 256, 0, stream>>>(x, xpad);
  wcvt_kernel<<<256, 256, 0, stream>>>(w_ctx, wb7, 49);
  wcvt_kernel<<<256, 256, 0, stream>>>(w_wide, wb5, 25);
  fcvt_kernel<<<512, 256, 0, stream>>>(w_comb, wcombH, 131072);
  fcvt_kernel<<<32, 256, 0, stream>>>(w_q, wqkH, 8192);
  fcvt_kernel<<<32, 256, 0, stream>>>(w_k, wqkH + 8192, 8192);
  fcvt_kernel<<<256, 256, 0, stream>>>(w_v, wvH, 65536);

  conv_both_kernel<<<512, 512, 0, stream>>>(xpad, wb7, wb5, b_ctx, b_wide, ctx_t);

  gemm_nmajor_kernel<512, 256, 0><<<dim3(256, 4), 64, 0, stream>>>(
      ctx_t, wcombH, b_comb, nullptr, multi_t);
  gemm_nmajor_kernel<256, 64, 1><<<dim3(256, 1), 64, 0, stream>>>(
      multi_t, wqkH, b_q, b_k, qkt_h);
  gemm_v_kernel<<<dim3(256, 4), 64, 0, stream>>>(multi_t, wvH, b_v, vbuf);

  attn_stats_kernel<<<512, 256, 0, stream>>>(qkt_h, rowmaxP, rowsumP);
  attn_out_kernel<<<256, 512, 0, stream>>>(qkt_h, vbuf, rowmaxP, rowsumP,
                                           mask, out);
}

// Round 9
// 528.027 us; speedup vs baseline: 1.1077x; 1.0020x over previous
//
#include <hip/hip_runtime.h>
#include <math.h>

#define BB 4
#define CC 256
#define HH 64
#define WW 64
#define NN 4096   // H*W

typedef _Float16 f16x8 __attribute__((ext_vector_type(8)));
typedef float f32x4 __attribute__((ext_vector_type(4)));

// ---------------------------------------------------------------------------
// pad + transpose: xpad[b][pr][pc][ci] = x[b][ci][pr-6][pc-6]  (f16, 0-padded)
// ---------------------------------------------------------------------------
__global__ __launch_bounds__(256) void pad_kernel(
    const float* __restrict__ x, _Float16* __restrict__ xpad)
{
  int blk = blockIdx.x;
  int pr = blk % 76;
  int b  = blk / 76;
  int ci = threadIdx.x;
  int r = pr - 6;
  _Float16* dst = xpad + (((size_t)b*76 + pr)*76)*256 + ci;
  if (r < 0 || r >= HH) {
    for (int pc = 0; pc < 76; ++pc) dst[(size_t)pc*256] = (_Float16)0.f;
  } else {
    const float* src = x + ((size_t)b*CC + ci)*NN + (size_t)r*WW;
    for (int pc = 0; pc < 76; ++pc) {
      int c = pc - 6;
      float v = (c >= 0 && c < WW) ? src[c] : 0.f;
      dst[(size_t)pc*256] = (_Float16)v;
    }
  }
}

// ---------------------------------------------------------------------------
// conv weight convert: dst[t][co][ci] = (f16) src[co][ci][t]
// ---------------------------------------------------------------------------
__global__ __launch_bounds__(256) void wcvt_kernel(
    const float* __restrict__ src, _Float16* __restrict__ dst, int T)
{
  int co = blockIdx.x;
  int ci = threadIdx.x;
  const float* s = src + ((size_t)co*256 + ci)*T;
  for (int t = 0; t < T; ++t)
    dst[(size_t)t*65536 + co*256 + ci] = (_Float16)s[t];
}

// ---------------------------------------------------------------------------
// generic flat f32 -> f16 convert
// ---------------------------------------------------------------------------
__global__ __launch_bounds__(256) void fcvt_kernel(
    const float* __restrict__ src, _Float16* __restrict__ dst, int n)
{
  int i = blockIdx.x * 256 + threadIdx.x;
  if (i < n) dst[i] = (_Float16)src[i];
}

// ---------------------------------------------------------------------------
// implicit-GEMM conv body via MFMA 16x16x32 f16.  Weight loads batched 4-ks
// at a time into registers (2 latency waits per kw instead of 8).  Direct
// global->LDS staging (no spill).  Epilogue: LDS-transpose (stride 136 f16)
// -> ctx_t[b][n][512]+c_off.
// ---------------------------------------------------------------------------
template<int KS, int DIL>
__device__ __forceinline__ void conv_body(
    int blk, const _Float16* __restrict__ xpad, const _Float16* __restrict__ wb,
    const float* __restrict__ bias, _Float16* __restrict__ ctx_t, int c_off,
    char* xs)
{
  int ytile = blk & 31;
  int cot = (blk >> 5) & 1;
  int b = blk >> 6;
  int y0 = ytile * 2;
  int tid = threadIdx.x;
  int lane = tid & 63;
  int wv = tid >> 6;
  int wco = wv >> 1;           // 0..3  -> co strip of 32
  int wsp = wv & 1;            // row y0+wsp
  int l15 = lane & 15;
  int lg  = lane >> 4;

  f32x4 acc[2][4];
  #pragma unroll
  for (int m = 0; m < 2; ++m)
    #pragma unroll
    for (int n = 0; n < 4; ++n) acc[m][n] = (f32x4){0.f, 0.f, 0.f, 0.f};

  for (int kh = 0; kh < KS; ++kh) {
    int prow = 6 + y0 + (kh - KS/2) * DIL;
    const uint4* src = (const uint4*)(xpad + (((size_t)b*76 + prow)*76)*256);
    __syncthreads();   // previous compute done reading xs
    #pragma unroll
    for (int i = 0; i < 10; ++i) {
      int ch = tid + i*512;               // 16B chunks; 2 rows = 4864 chunks
      if (ch < 4864) {
        uint4 v = src[ch];
        int r = ch >> 5, cq = ch & 31;
        *(uint4*)(xs + r*512 + ((cq << 4) ^ ((r & 7) << 4))) = v;
      }
    }
    __syncthreads();
    for (int kw = 0; kw < KS; ++kw) {
      int dx = (kw - KS/2) * DIL;
      int tap = kh*KS + kw;
      const _Float16* wt = wb + ((size_t)tap << 16)
                              + ((size_t)(cot*128 + wco*32 + l15) << 8) + (lg << 3);
      #pragma unroll
      for (int half = 0; half < 2; ++half) {
        // batch 8 weight loads (4 ks x {a0,a1}) -> one latency wait
        f16x8 w0[4], w1[4];
        #pragma unroll
        for (int kq = 0; kq < 4; ++kq) {
          int ks = half*4 + kq;
          w0[kq] = *(const f16x8*)(wt + ks*32);
          w1[kq] = *(const f16x8*)(wt + 16*256 + ks*32);
        }
        #pragma unroll
        for (int kq = 0; kq < 4; ++kq) {
          int ks = half*4 + kq;
          #pragma unroll
          for (int nf = 0; nf < 4; ++nf) {
            int r = wsp*76 + 6 + nf*16 + l15 + dx;
            f16x8 bf = *(const f16x8*)(xs + r*512 + ((ks*64 + (lg << 4)) ^ ((r & 7) << 4)));
            acc[0][nf] = __builtin_amdgcn_mfma_f32_16x16x32_f16(w0[kq], bf, acc[0][nf], 0, 0, 0);
            acc[1][nf] = __builtin_amdgcn_mfma_f32_16x16x32_f16(w1[kq], bf, acc[1][nf], 0, 0, 0);
          }
        }
      }
    }
  }

  // epilogue: LDS transpose tile [128 n][stride 136 co], then coalesced write
  __syncthreads();
  _Float16* ep = (_Float16*)xs;
  #pragma unroll
  for (int m = 0; m < 2; ++m)
    #pragma unroll
    for (int i = 0; i < 4; ++i) {
      int co_l = wco*32 + m*16 + lg*4 + i;
      float bs = bias[cot*128 + co_l];
      #pragma unroll
      for (int nf = 0; nf < 4; ++nf) {
        int n_l = wsp*64 + nf*16 + l15;
        ep[n_l*136 + co_l] = (_Float16)(acc[m][nf][i] + bs);
      }
    }
  __syncthreads();
  const int cbase = c_off + cot*128;
  #pragma unroll
  for (int it = 0; it < 4; ++it) {
    int idx = tid + it*512;
    int n_l = idx >> 4, q = idx & 15;
    f16x8 val = *(const f16x8*)(ep + n_l*136 + q*8);
    *(f16x8*)(ctx_t + ((size_t)b*4096 + (size_t)y0*64 + n_l)*512 + cbase + q*8) = val;
  }
}

// ---------------------------------------------------------------------------
// merged conv dispatch: blocks 0..255 -> conv7 (dil 1), 256..511 -> conv5
// (dil 3).  __launch_bounds__(512,4): 2 blocks/CU co-resident.
// ---------------------------------------------------------------------------
__global__ __launch_bounds__(512, 4) void conv_both_kernel(
    const _Float16* __restrict__ xpad,
    const _Float16* __restrict__ wb7, const _Float16* __restrict__ wb5,
    const float* __restrict__ b7, const float* __restrict__ b5,
    _Float16* __restrict__ ctx_t)
{
  __shared__ __align__(16) char xs[2*76*512];
  if (blockIdx.x < 256)
    conv_body<7, 1>(blockIdx.x, xpad, wb7, b7, ctx_t, 0, xs);
  else
    conv_body<5, 3>(blockIdx.x - 256, xpad, wb5, b5, ctx_t, 256, xs);
}

// ---------------------------------------------------------------------------
// GEMM producing n-major output: out[n][O] = A[n][K] . Wt[o][K]^T + bias
// grid (n-tiles of 64 over 16384, O/64), 64 threads (1 wave), acc 4x4 frags.
// ---------------------------------------------------------------------------
template<int K, int O, int BIASMODE>
__global__ __launch_bounds__(64) void gemm_nmajor_kernel(
    const _Float16* __restrict__ A, const _Float16* __restrict__ Wt,
    const float* __restrict__ bias0, const float* __restrict__ bias1,
    _Float16* __restrict__ outh)
{
  int nt = blockIdx.x;
  int ot = blockIdx.y;
  int lane = threadIdx.x;
  int l15 = lane & 15, lg = lane >> 4;
  int n0 = nt*64, o0 = ot*64;
  f32x4 acc[4][4] = {};
  for (int k0 = 0; k0 < K; k0 += 32) {
    f16x8 a[4], bfr[4];
    #pragma unroll
    for (int f = 0; f < 4; ++f)
      a[f] = *(const f16x8*)(A + (size_t)(n0 + f*16 + l15)*K + k0 + lg*8);
    #pragma unroll
    for (int f = 0; f < 4; ++f)
      bfr[f] = *(const f16x8*)(Wt + (size_t)(o0 + f*16 + l15)*K + k0 + lg*8);
    #pragma unroll
    for (int i = 0; i < 4; ++i)
      #pragma unroll
      for (int j = 0; j < 4; ++j)
        acc[i][j] = __builtin_amdgcn_mfma_f32_16x16x32_f16(a[i], bfr[j], acc[i][j], 0, 0, 0);
  }
  #pragma unroll
  for (int i = 0; i < 4; ++i)
    #pragma unroll
    for (int j = 0; j < 4; ++j)
      #pragma unroll
      for (int r = 0; r < 4; ++r) {
        int n = n0 + i*16 + lg*4 + r;
        int o = o0 + j*16 + l15;
        float bs = (BIASMODE == 0) ? bias0[o] : (o < 32 ? bias0[o] : bias1[o - 32]);
        outh[(size_t)n*O + o] = (_Float16)(acc[i][j][r] + bs);
      }
}

// ---------------------------------------------------------------------------
// v GEMM: v[b][c][n] = Wv[c][m] . multi_t[n][m]^T + bias  (c-major out)
// ---------------------------------------------------------------------------
__global__ __launch_bounds__(64) void gemm_v_kernel(
    const _Float16* __restrict__ M, const _Float16* __restrict__ Wv,
    const float* __restrict__ bias, _Float16* __restrict__ v)
{
  int nt = blockIdx.x;          // over 16384/64
  int ct = blockIdx.y;          // 0..3
  int lane = threadIdx.x;
  int l15 = lane & 15, lg = lane >> 4;
  int n0 = nt*64, c0 = ct*64;
  f32x4 acc[4][4] = {};
  for (int k0 = 0; k0 < 256; k0 += 32) {
    f16x8 a[4], bfr[4];
    #pragma unroll
    for (int f = 0; f < 4; ++f)
      a[f] = *(const f16x8*)(Wv + (size_t)(c0 + f*16 + l15)*256 + k0 + lg*8);
    #pragma unroll
    for (int f = 0; f < 4; ++f)
      bfr[f] = *(const f16x8*)(M + (size_t)(n0 + f*16 + l15)*256 + k0 + lg*8);
    #pragma unroll
    for (int i = 0; i < 4; ++i)
      #pragma unroll
      for (int j = 0; j < 4; ++j)
        acc[i][j] = __builtin_amdgcn_mfma_f32_16x16x32_f16(a[i], bfr[j], acc[i][j], 0, 0, 0);
  }
  #pragma unroll
  for (int i = 0; i < 4; ++i)
    #pragma unroll
    for (int j = 0; j < 4; ++j)
      #pragma unroll
      for (int r = 0; r < 4; ++r) {
        int c = c0 + i*16 + lg*4 + r;
        int n_abs = n0 + j*16 + l15;
        int b = n_abs >> 12, n = n_abs & 4095;
        v[((size_t)(b*256 + c))*4096 + n] = (_Float16)(acc[i][j][r] + bias[c]);
      }
}

// ---------------------------------------------------------------------------
// attention pass A: per-row running max + sum(exp) over an n-half.
// qkt layout [16384][64] f16: cols 0..31 = q, 32..63 = k.
// grid 512 = b(4) x mt(64) x nh(2), 256 threads (4 waves, 16 m-rows each).
// ---------------------------------------------------------------------------
__global__ __launch_bounds__(256) void attn_stats_kernel(
    const _Float16* __restrict__ qh,
    float* __restrict__ rowmaxP, float* __restrict__ rowsumP)
{
  int blk = blockIdx.x;
  int b = blk >> 7, mt = (blk >> 1) & 63, nh = blk & 1;
  int tid = threadIdx.x, lane = tid & 63, w = tid >> 6;
  int l15 = lane & 15, lg = lane >> 4;
  size_t bN = (size_t)b * 4096;
  int mrow = mt*64 + w*16;
  f16x8 ah = *(const f16x8*)(qh + (bN + mrow + l15)*64 + lg*8);
  float rm[4] = {-3e38f, -3e38f, -3e38f, -3e38f};
  float sm[4] = {0.f, 0.f, 0.f, 0.f};
  for (int n0 = nh*2048; n0 < nh*2048 + 2048; n0 += 16) {
    f16x8 bh = *(const f16x8*)(qh + (bN + n0 + l15)*64 + 32 + lg*8);
    f32x4 s = {};
    s = __builtin_amdgcn_mfma_f32_16x16x32_f16(ah, bh, s, 0, 0, 0);
    #pragma unroll
    for (int i = 0; i < 4; ++i) {
      float nm = fmaxf(rm[i], s[i]);
      sm[i] = sm[i]*__expf(rm[i] - nm) + __expf(s[i] - nm);
      rm[i] = nm;
    }
  }
  #pragma unroll
  for (int off = 1; off <= 8; off <<= 1) {
    #pragma unroll
    for (int i = 0; i < 4; ++i) {
      float rmo = __shfl_xor(rm[i], off);
      float smo = __shfl_xor(sm[i], off);
      float M = fmaxf(rm[i], rmo);
      sm[i] = sm[i]*__expf(rm[i] - M) + smo*__expf(rmo - M);
      rm[i] = M;
    }
  }
  if (l15 == 0) {
    #pragma unroll
    for (int i = 0; i < 4; ++i) {
      size_t idx = (size_t)nh*16384 + bN + mrow + lg*4 + i;
      rowmaxP[idx] = rm[i];
      rowsumP[idx] = sm[i];
    }
  }
}

// ---------------------------------------------------------------------------
// attention pass B: O[m64][c256] = P . V^T with P recomputed per 32-n chunk.
// grid 256 = b(4) x mt(64), 512 threads (8 waves).
// vs/pl strides = 40 f16 (80B): 16B-aligned rows for ds_read_b128.
// ---------------------------------------------------------------------------
__global__ __launch_bounds__(512) void attn_out_kernel(
    const _Float16* __restrict__ qh, const _Float16* __restrict__ v,
    const float* __restrict__ rowmaxP, const float* __restrict__ rowsumP,
    const float* __restrict__ mask, float* __restrict__ out)
{
  __shared__ union U {
    struct { __align__(16) _Float16 vs[256*40]; __align__(16) _Float16 pl[64*40]; } s;
    float epi[256*68];
  } u;
  int blk = blockIdx.x;
  int b = blk >> 6, mt = blk & 63;
  int tid = threadIdx.x, lane = tid & 63, w = tid >> 6;
  int l15 = lane & 15, lg = lane >> 4;
  size_t bN = (size_t)b * 4096;
  int m0 = mt*64;

  // QK role
  int mf = w >> 1, nf2 = w & 1;
  f16x8 ah = *(const f16x8*)(qh + (bN + m0 + mf*16 + l15)*64 + lg*8);
  float rm[4], rsi[4];
  #pragma unroll
  for (int i = 0; i < 4; ++i) {
    size_t m = bN + m0 + mf*16 + lg*4 + i;
    float r0 = rowmaxP[m], r1 = rowmaxP[16384 + m];
    float s0 = rowsumP[m], s1 = rowsumP[16384 + m];
    float M = fmaxf(r0, r1);
    rm[i] = M;
    rsi[i] = 1.0f / (s0*__expf(r0 - M) + s1*__expf(r1 - M));
  }
  // PV role
  int mh = w >> 2, cw = (w & 3)*64;
  f32x4 acc[2][4] = {};
  const _Float16* vb = v + (size_t)b*256*4096;

  for (int n0 = 0; n0 < 4096; n0 += 32) {
    // stage v tile [256 c][32 n] (stride 40 f16)
    #pragma unroll
    for (int it = 0; it < 2; ++it) {
      int idx = tid + it*512;
      int c = idx >> 2, q = idx & 3;
      *(f16x8*)(u.s.vs + c*40 + q*8) = *(const f16x8*)(vb + (size_t)c*4096 + n0 + q*8);
    }
    // QK + exp -> P (f16) in LDS
    {
      f16x8 bh = *(const f16x8*)(qh + (bN + n0 + nf2*16 + l15)*64 + 32 + lg*8);
      f32x4 s = {};
      s = __builtin_amdgcn_mfma_f32_16x16x32_f16(ah, bh, s, 0, 0, 0);
      #pragma unroll
      for (int i = 0; i < 4; ++i) {
        float p = __expf(s[i] - rm[i]) * rsi[i];
        u.s.pl[(mf*16 + lg*4 + i)*40 + nf2*16 + l15] = (_Float16)p;
      }
    }
    __syncthreads();
    // PV
    {
      f16x8 pa[2], pb[4];
      #pragma unroll
      for (int af = 0; af < 2; ++af)
        pa[af] = *(const f16x8*)(u.s.pl + (mh*32 + af*16 + l15)*40 + lg*8);
      #pragma unroll
      for (int bf = 0; bf < 4; ++bf)
        pb[bf] = *(const f16x8*)(u.s.vs + (cw + bf*16 + l15)*40 + lg*8);
      #pragma unroll
      for (int af = 0; af < 2; ++af)
        #pragma unroll
        for (int bf = 0; bf < 4; ++bf)
          acc[af][bf] = __builtin_amdgcn_mfma_f32_16x16x32_f16(pa[af], pb[bf], acc[af][bf], 0, 0, 0);
    }
    __syncthreads();
  }

  // epilogue: transpose via LDS, apply (1+mask), write out[b][c][m]
  #pragma unroll
  for (int af = 0; af < 2; ++af)
    #pragma unroll
    for (int bf = 0; bf < 4; ++bf)
      #pragma unroll
      for (int r = 0; r < 4; ++r) {
        int c = cw + bf*16 + l15;
        int ml = mh*32 + af*16 + lg*4 + r;
        u.epi[c*68 + ml] = acc[af][bf][r];
      }
  __syncthreads();
  const float* mb = mask + (size_t)b*65536 + (size_t)(mt*4)*256;
  #pragma unroll
  for (int it = 0; it < 8; ++it) {
    int idx = tid + it*512;
    int c = idx >> 4, q = idx & 15;
    f32x4 val = *(const f32x4*)(u.epi + c*68 + q*4);
    f32x4 o4;
    #pragma unroll
    for (int jj = 0; jj < 4; ++jj) {
      int xcol = q*4 + jj;
      o4[jj] = val[jj] * (1.0f + mb[xcol*4]);
    }
    *(f32x4*)(out + ((size_t)b*256 + c)*4096 + m0 + q*4) = o4;
  }
}

// ---------------------------------------------------------------------------
extern "C" void kernel_launch(void* const* d_in, const int* in_sizes, int n_in,
                              void* d_out, int out_size, void* d_ws, size_t ws_size,
                              hipStream_t stream)
{
  (void)in_sizes; (void)n_in; (void)out_size; (void)ws_size;
  const float* x      = (const float*)d_in[0];
  const float* mask   = (const float*)d_in[1];
  const float* w_ctx  = (const float*)d_in[2];
  const float* b_ctx  = (const float*)d_in[3];
  const float* w_wide = (const float*)d_in[4];
  const float* b_wide = (const float*)d_in[5];
  const float* w_comb = (const float*)d_in[6];
  const float* b_comb = (const float*)d_in[7];
  const float* w_q    = (const float*)d_in[8];
  const float* b_q    = (const float*)d_in[9];
  const float* w_k    = (const float*)d_in[10];
  const float* b_k    = (const float*)d_in[11];
  const float* w_v    = (const float*)d_in[12];
  const float* b_v    = (const float*)d_in[13];
  float* out = (float*)d_out;

  float* ws = (float*)d_ws;
  // --- phase-aliased layout (float offsets). Total 9,682,944 fl = 38.7 MB.
  // Phase 1 (pre/conv):
  _Float16* xpad    = (_Float16*)(ws);             // [0, 2,957,312)
  _Float16* wb7     = (_Float16*)(ws + 2957312);   // 49*65536 f16
  _Float16* wb5     = (_Float16*)(ws + 4562944);   // 25*65536 f16
  _Float16* ctx_t   = (_Float16*)(ws + 5382144);   // 16384*512 f16
  _Float16* wcombH  = (_Float16*)(ws + 9576448);   // 256*512 f16
  _Float16* wqkH    = (_Float16*)(ws + 9641984);   // 64*256 f16
  _Float16* wvH     = (_Float16*)(ws + 9650176);   // 256*256 f16
  // Phase 2 (after convs; xpad/wb7/wb5 dead, ctx_t live):
  _Float16* multi_t = (_Float16*)(ws);             // 16384*256 f16
  _Float16* qkt_h   = (_Float16*)(ws + 2097152);   // 16384*64 f16
  float*    rowmaxP = ws + 2621440;                // 2*16384 f32
  float*    rowsumP = ws + 2654208;                // 2*16384 f32
  // Phase 3 (after combine; ctx_t dead):
  _Float16* vbuf    = (_Float16*)(ws + 5382144);   // 4*256*4096 f16

  pad_kernel<<<BB*76, 256, 0, stream>>>(x, xpad);
  wcvt_kernel<<<256, 256, 0, stream>>>(w_ctx, wb7, 49);
  wcvt_kernel<<<256, 256, 0, stream>>>(w_wide, wb5, 25);
  fcvt_kernel<<<512, 256, 0, stream>>>(w_comb, wcombH, 131072);
  fcvt_kernel<<<32, 256, 0, stream>>>(w_q, wqkH, 8192);
  fcvt_kernel<<<32, 256, 0, stream>>>(w_k, wqkH + 8192, 8192);
  fcvt_kernel<<<256, 256, 0, stream>>>(w_v, wvH, 65536);

  conv_both_kernel<<<512, 512, 0, stream>>>(xpad, wb7, wb5, b_ctx, b_wide, ctx_t);

  gemm_nmajor_kernel<512, 256, 0><<<dim3(256, 4), 64, 0, stream>>>(
      ctx_t, wcombH, b_comb, nullptr, multi_t);
  gemm_nmajor_kernel<256, 64, 1><<<dim3(256, 1), 64, 0, stream>>>(
      multi_t, wqkH, b_q, b_k, qkt_h);
  gemm_v_kernel<<<dim3(256, 4), 64, 0, stream>>>(multi_t, wvH, b_v, vbuf);

  attn_stats_kernel<<<512, 256, 0, stream>>>(qkt_h, rowmaxP, rowsumP);
  attn_out_kernel<<<256, 512, 0, stream>>>(qkt_h, vbuf, rowmaxP, rowsumP,
                                           mask, out);
}